// Round 1
// baseline (1618.925 us; speedup 1.0000x reference)
//
#include <hip/hip_runtime.h>
#include <hip/hip_bf16.h>

#define DDIM 64

// ---------------------------------------------------------------------------
// Kernel A: per-node message MLP.  M = relu(relu(h@W1+b1)@W2+b2)
// (gather commutes with row-wise MLP, so compute per-node not per-edge: 16x
// fewer FLOPs than the literal reference)
// ---------------------------------------------------------------------------
__global__ __launch_bounds__(256) void node_mlp(
    const float* __restrict__ h,
    const float* __restrict__ W1, const float* __restrict__ b1,
    const float* __restrict__ W2, const float* __restrict__ b2,
    float* __restrict__ M, int n_nodes)
{
    __shared__ float w1[DDIM * DDIM];
    __shared__ float w2[DDIM * DDIM];
    __shared__ float bb1[DDIM];
    __shared__ float bb2[DDIM];

    const int t = threadIdx.x;
    for (int i = t; i < DDIM * DDIM; i += 256) { w1[i] = W1[i]; w2[i] = W2[i]; }
    if (t < DDIM) { bb1[t] = b1[t]; bb2[t] = b2[t]; }
    __syncthreads();

    const int node = blockIdx.x * 256 + t;
    if (node >= n_nodes) return;

    float in[DDIM];
    float acc[DDIM];

    const float4* h4 = (const float4*)(h + (size_t)node * DDIM);
#pragma unroll
    for (int k = 0; k < DDIM / 4; k++) {
        float4 v = h4[k];
        in[4 * k + 0] = v.x; in[4 * k + 1] = v.y;
        in[4 * k + 2] = v.z; in[4 * k + 3] = v.w;
    }

    // layer 1
#pragma unroll
    for (int j = 0; j < DDIM; j++) acc[j] = bb1[j];
    for (int k = 0; k < DDIM; k++) {
        const float x = in[k];
        const float4* wr = (const float4*)(w1 + k * DDIM);
#pragma unroll
        for (int j4 = 0; j4 < DDIM / 4; j4++) {
            float4 w = wr[j4];
            acc[4 * j4 + 0] += x * w.x; acc[4 * j4 + 1] += x * w.y;
            acc[4 * j4 + 2] += x * w.z; acc[4 * j4 + 3] += x * w.w;
        }
    }
#pragma unroll
    for (int j = 0; j < DDIM; j++) in[j] = fmaxf(acc[j], 0.0f);

    // layer 2
#pragma unroll
    for (int j = 0; j < DDIM; j++) acc[j] = bb2[j];
    for (int k = 0; k < DDIM; k++) {
        const float x = in[k];
        const float4* wr = (const float4*)(w2 + k * DDIM);
#pragma unroll
        for (int j4 = 0; j4 < DDIM / 4; j4++) {
            float4 w = wr[j4];
            acc[4 * j4 + 0] += x * w.x; acc[4 * j4 + 1] += x * w.y;
            acc[4 * j4 + 2] += x * w.z; acc[4 * j4 + 3] += x * w.w;
        }
    }

    float4* M4 = (float4*)(M + (size_t)node * DDIM);
#pragma unroll
    for (int j4 = 0; j4 < DDIM / 4; j4++) {
        float4 v;
        v.x = fmaxf(acc[4 * j4 + 0], 0.0f);
        v.y = fmaxf(acc[4 * j4 + 1], 0.0f);
        v.z = fmaxf(acc[4 * j4 + 2], 0.0f);
        v.w = fmaxf(acc[4 * j4 + 3], 0.0f);
        M4[j4] = v;
    }
}

// ---------------------------------------------------------------------------
// Kernel B: scatter-add over edges.  agg[row] += M[col]; deg[row] += 1
// 16 lanes per edge, each lane moves one float4 (4 hw fp32 atomics).
// ---------------------------------------------------------------------------
__global__ __launch_bounds__(256) void scatter_edges(
    const int* __restrict__ eidx,   // [2, E] flattened: rows then cols
    const float* __restrict__ M,
    float* __restrict__ agg,
    unsigned int* __restrict__ deg,
    int n_edges)
{
    const int tid = blockIdx.x * 256 + threadIdx.x;
    const int e = tid >> 4;
    const int l = tid & 15;
    if (e >= n_edges) return;

    const int row = eidx[e];
    const int col = eidx[n_edges + e];

    float4 v = ((const float4*)M)[(size_t)col * (DDIM / 4) + l];
    float* dst = agg + (size_t)row * DDIM + l * 4;
    unsafeAtomicAdd(dst + 0, v.x);
    unsafeAtomicAdd(dst + 1, v.y);
    unsafeAtomicAdd(dst + 2, v.z);
    unsafeAtomicAdd(dst + 3, v.w);
    if (l == 0) atomicAdd(deg + row, 1u);
}

// ---------------------------------------------------------------------------
// Kernel C: degree-normalize + update MLP.
// z = relu([h, agg/deg] @ U1 + c1); out = z @ U2 + c2
// ---------------------------------------------------------------------------
__global__ __launch_bounds__(256) void update_mlp(
    const float* __restrict__ h,
    const float* __restrict__ agg,
    const unsigned int* __restrict__ deg,
    const float* __restrict__ U1, const float* __restrict__ c1,
    const float* __restrict__ U2, const float* __restrict__ c2,
    float* __restrict__ out, int n_nodes)
{
    __shared__ float u1[2 * DDIM * DDIM];   // (128, 64) row-major
    __shared__ float cc1[DDIM];
    __shared__ float u2[DDIM * 2];
    __shared__ float cc2[2];

    const int t = threadIdx.x;
    for (int i = t; i < 2 * DDIM * DDIM; i += 256) u1[i] = U1[i];
    if (t < DDIM) cc1[t] = c1[t];
    if (t < DDIM * 2) u2[t] = U2[t];
    if (t < 2) cc2[t] = c2[t];
    __syncthreads();

    const int node = blockIdx.x * 256 + t;
    if (node >= n_nodes) return;

    float in[DDIM];
    float acc[DDIM];
#pragma unroll
    for (int j = 0; j < DDIM; j++) acc[j] = cc1[j];

    // ---- h part (U1 rows 0..63) ----
    const float4* h4 = (const float4*)(h + (size_t)node * DDIM);
#pragma unroll
    for (int k = 0; k < DDIM / 4; k++) {
        float4 v = h4[k];
        in[4 * k + 0] = v.x; in[4 * k + 1] = v.y;
        in[4 * k + 2] = v.z; in[4 * k + 3] = v.w;
    }
    for (int k = 0; k < DDIM; k++) {
        const float x = in[k];
        const float4* wr = (const float4*)(u1 + k * DDIM);
#pragma unroll
        for (int j4 = 0; j4 < DDIM / 4; j4++) {
            float4 w = wr[j4];
            acc[4 * j4 + 0] += x * w.x; acc[4 * j4 + 1] += x * w.y;
            acc[4 * j4 + 2] += x * w.z; acc[4 * j4 + 3] += x * w.w;
        }
    }

    // ---- agg part (U1 rows 64..127), degree-normalized ----
    const float dnorm = 1.0f / fmaxf((float)deg[node], 1.0f);
    const float4* a4 = (const float4*)(agg + (size_t)node * DDIM);
#pragma unroll
    for (int k = 0; k < DDIM / 4; k++) {
        float4 v = a4[k];
        in[4 * k + 0] = v.x * dnorm; in[4 * k + 1] = v.y * dnorm;
        in[4 * k + 2] = v.z * dnorm; in[4 * k + 3] = v.w * dnorm;
    }
    for (int k = 0; k < DDIM; k++) {
        const float x = in[k];
        const float4* wr = (const float4*)(u1 + (DDIM + k) * DDIM);
#pragma unroll
        for (int j4 = 0; j4 < DDIM / 4; j4++) {
            float4 w = wr[j4];
            acc[4 * j4 + 0] += x * w.x; acc[4 * j4 + 1] += x * w.y;
            acc[4 * j4 + 2] += x * w.z; acc[4 * j4 + 3] += x * w.w;
        }
    }

    // ---- output layer ----
    float o0 = cc2[0], o1 = cc2[1];
#pragma unroll
    for (int j = 0; j < DDIM; j++) {
        const float z = fmaxf(acc[j], 0.0f);
        o0 += z * u2[2 * j + 0];
        o1 += z * u2[2 * j + 1];
    }
    ((float2*)out)[node] = make_float2(o0, o1);
}

// ---------------------------------------------------------------------------
extern "C" void kernel_launch(void* const* d_in, const int* in_sizes, int n_in,
                              void* d_out, int out_size, void* d_ws, size_t ws_size,
                              hipStream_t stream) {
    const float* h    = (const float*)d_in[0];
    const int*   eidx = (const int*)d_in[1];
    const float* W1   = (const float*)d_in[2];
    const float* b1   = (const float*)d_in[3];
    const float* W2   = (const float*)d_in[4];
    const float* b2   = (const float*)d_in[5];
    const float* U1   = (const float*)d_in[6];
    const float* c1   = (const float*)d_in[7];
    const float* U2   = (const float*)d_in[8];
    const float* c2   = (const float*)d_in[9];

    const int n_nodes = in_sizes[0] / DDIM;     // 100000
    const int n_edges = in_sizes[1] / 2;        // 1600000

    // workspace layout
    float*        M   = (float*)d_ws;                                   // N*64 f32
    float*        agg = M + (size_t)n_nodes * DDIM;                     // N*64 f32
    unsigned int* deg = (unsigned int*)(agg + (size_t)n_nodes * DDIM);  // N u32

    float* out = (float*)d_out;

    // zero agg + deg (contiguous)
    hipMemsetAsync(agg, 0, ((size_t)n_nodes * DDIM + n_nodes) * sizeof(float), stream);

    const int nblk_nodes = (n_nodes + 255) / 256;
    node_mlp<<<nblk_nodes, 256, 0, stream>>>(h, W1, b1, W2, b2, M, n_nodes);

    const int nblk_edges = (n_edges * 16 + 255) / 256;
    scatter_edges<<<nblk_edges, 256, 0, stream>>>(eidx, M, agg, deg, n_edges);

    update_mlp<<<nblk_nodes, 256, 0, stream>>>(h, agg, deg, U1, c1, U2, c2, out, n_nodes);
}

// Round 2
// 453.936 us; speedup vs baseline: 3.5664x; 3.5664x over previous
//
#include <hip/hip_runtime.h>
#include <hip/hip_bf16.h>

#define DDIM 64
typedef unsigned int u32;

// ---------------------------------------------------------------------------
// Kernel A: per-node message MLP.  M = relu(relu(h@W1+b1)@W2+b2)
// (gather commutes with row-wise MLP: per-node, not per-edge — 16x fewer FLOPs)
// ---------------------------------------------------------------------------
__global__ __launch_bounds__(256) void node_mlp(
    const float* __restrict__ h,
    const float* __restrict__ W1, const float* __restrict__ b1,
    const float* __restrict__ W2, const float* __restrict__ b2,
    float* __restrict__ M, int n_nodes)
{
    __shared__ float w1[DDIM * DDIM];
    __shared__ float w2[DDIM * DDIM];
    __shared__ float bb1[DDIM];
    __shared__ float bb2[DDIM];

    const int t = threadIdx.x;
    for (int i = t; i < DDIM * DDIM; i += 256) { w1[i] = W1[i]; w2[i] = W2[i]; }
    if (t < DDIM) { bb1[t] = b1[t]; bb2[t] = b2[t]; }
    __syncthreads();

    const int node = blockIdx.x * 256 + t;
    if (node >= n_nodes) return;

    float in[DDIM];
    float acc[DDIM];

    const float4* h4 = (const float4*)(h + (size_t)node * DDIM);
#pragma unroll
    for (int k = 0; k < DDIM / 4; k++) {
        float4 v = h4[k];
        in[4 * k + 0] = v.x; in[4 * k + 1] = v.y;
        in[4 * k + 2] = v.z; in[4 * k + 3] = v.w;
    }

#pragma unroll
    for (int j = 0; j < DDIM; j++) acc[j] = bb1[j];
    for (int k = 0; k < DDIM; k++) {
        const float x = in[k];
        const float4* wr = (const float4*)(w1 + k * DDIM);
#pragma unroll
        for (int j4 = 0; j4 < DDIM / 4; j4++) {
            float4 w = wr[j4];
            acc[4 * j4 + 0] += x * w.x; acc[4 * j4 + 1] += x * w.y;
            acc[4 * j4 + 2] += x * w.z; acc[4 * j4 + 3] += x * w.w;
        }
    }
#pragma unroll
    for (int j = 0; j < DDIM; j++) in[j] = fmaxf(acc[j], 0.0f);

#pragma unroll
    for (int j = 0; j < DDIM; j++) acc[j] = bb2[j];
    for (int k = 0; k < DDIM; k++) {
        const float x = in[k];
        const float4* wr = (const float4*)(w2 + k * DDIM);
#pragma unroll
        for (int j4 = 0; j4 < DDIM / 4; j4++) {
            float4 w = wr[j4];
            acc[4 * j4 + 0] += x * w.x; acc[4 * j4 + 1] += x * w.y;
            acc[4 * j4 + 2] += x * w.z; acc[4 * j4 + 3] += x * w.w;
        }
    }

    float4* M4 = (float4*)(M + (size_t)node * DDIM);
#pragma unroll
    for (int j4 = 0; j4 < DDIM / 4; j4++) {
        float4 v;
        v.x = fmaxf(acc[4 * j4 + 0], 0.0f);
        v.y = fmaxf(acc[4 * j4 + 1], 0.0f);
        v.z = fmaxf(acc[4 * j4 + 2], 0.0f);
        v.w = fmaxf(acc[4 * j4 + 3], 0.0f);
        M4[j4] = v;
    }
}

// ---------------------------------------------------------------------------
// CSR construction: histogram -> exclusive scan -> counting-sort fill
// ---------------------------------------------------------------------------
__global__ __launch_bounds__(256) void hist_rows(
    const int* __restrict__ eidx, u32* __restrict__ deg, int n_edges)
{
    const int e = blockIdx.x * 256 + threadIdx.x;
    if (e < n_edges) atomicAdd(&deg[eidx[e]], 1u);
}

__global__ __launch_bounds__(256) void scan_blocks(
    const u32* __restrict__ deg, u32* __restrict__ offsets,
    u32* __restrict__ bsums, int n)
{
    __shared__ u32 s[256];
    const int t = threadIdx.x;
    const int gid = blockIdx.x * 256 + t;
    u32 v = (gid < n) ? deg[gid] : 0u;
    s[t] = v;
    __syncthreads();
    for (int off = 1; off < 256; off <<= 1) {
        u32 x = (t >= off) ? s[t - off] : 0u;
        __syncthreads();
        s[t] += x;
        __syncthreads();
    }
    if (gid < n) offsets[gid] = s[t] - v;          // exclusive within block
    if (t == 255) bsums[blockIdx.x] = s[255];      // block total
}

__global__ __launch_bounds__(512) void scan_top(u32* __restrict__ bsums, int nb)
{
    __shared__ u32 s[512];
    const int t = threadIdx.x;
    u32 v = (t < nb) ? bsums[t] : 0u;
    s[t] = v;
    __syncthreads();
    for (int off = 1; off < 512; off <<= 1) {
        u32 x = (t >= off) ? s[t - off] : 0u;
        __syncthreads();
        s[t] += x;
        __syncthreads();
    }
    if (t < nb) bsums[t] = s[t] - v;               // exclusive
}

__global__ __launch_bounds__(256) void add_base(
    u32* __restrict__ offsets, const u32* __restrict__ bsums,
    int n, int n_edges)
{
    const int gid = blockIdx.x * 256 + threadIdx.x;
    if (gid < n) offsets[gid] += bsums[blockIdx.x];
    if (gid == 0) offsets[n] = (u32)n_edges;
}

__global__ __launch_bounds__(256) void fill_csr(
    const int* __restrict__ eidx, const u32* __restrict__ offsets,
    u32* __restrict__ cursor, u32* __restrict__ csr_col, int n_edges)
{
    const int e = blockIdx.x * 256 + threadIdx.x;
    if (e >= n_edges) return;
    const int row = eidx[e];
    const int col = eidx[n_edges + e];
    const u32 slot = offsets[row] + atomicAdd(&cursor[row], 1u);
    csr_col[slot] = (u32)col;
}

// ---------------------------------------------------------------------------
// Fused gather + update MLP.  16 lanes per node; lane l owns feature cols
// 4l..4l+3.  agg never hits HBM.
//   agg = mean_{col in CSR[node]} M[col]
//   z = relu([h, agg] @ U1 + c1);  out = z @ U2 + c2
// ---------------------------------------------------------------------------
#define INPAD 132   // 128 + 4 pad: distinct banks for the 4 node-groups/wave

__global__ __launch_bounds__(256) void gather_update(
    const float* __restrict__ h, const float* __restrict__ M,
    const u32* __restrict__ offsets, const u32* __restrict__ csr_col,
    const float* __restrict__ U1, const float* __restrict__ c1,
    const float* __restrict__ U2, const float* __restrict__ c2,
    float* __restrict__ out, int n_nodes)
{
    __shared__ __align__(16) float u1[2 * DDIM * DDIM];   // (128,64) row-major, 32 KB
    __shared__ __align__(16) float inb[16][INPAD];        // per-node [h|agg], 8.25 KB
    __shared__ float cc1[DDIM];
    __shared__ float u2[DDIM * 2];
    __shared__ float cc2v[2];

    const int t = threadIdx.x;
    {
        const float4* src = (const float4*)U1;
        float4* dst = (float4*)u1;
        for (int i = t; i < 2 * DDIM * DDIM / 4; i += 256) dst[i] = src[i];
    }
    if (t < DDIM) cc1[t] = c1[t];
    if (t < DDIM * 2) u2[t] = U2[t];
    if (t < 2) cc2v[t] = c2[t];

    const int nl = t >> 4;          // node-local index 0..15
    const int l  = t & 15;          // lane within node
    const int node = blockIdx.x * 16 + nl;
    const bool valid = node < n_nodes;

    // ---- gather: acc = sum over edges of M[col], lane's 4-col slice ----
    float ax = 0.f, ay = 0.f, az = 0.f, aw = 0.f;
    u32 beg = 0, end = 0;
    if (valid) { beg = offsets[node]; end = offsets[node + 1]; }
    for (u32 i = beg; i < end; i++) {
        const u32 col = csr_col[i];
        float4 v = ((const float4*)M)[(size_t)col * (DDIM / 4) + l];
        ax += v.x; ay += v.y; az += v.z; aw += v.w;
    }
    const float dn = 1.0f / fmaxf((float)(end - beg), 1.0f);

    if (valid) {
        float4 hv = ((const float4*)h)[(size_t)node * (DDIM / 4) + l];
        ((float4*)&inb[nl][0])[l] = hv;                       // in[0..63]  = h
        float4 an = make_float4(ax * dn, ay * dn, az * dn, aw * dn);
        ((float4*)&inb[nl][DDIM])[l] = an;                    // in[64..127] = agg/deg
    }
    __syncthreads();

    // ---- layer 1: thread computes z[4l..4l+3] ----
    float4 z = ((const float4*)cc1)[l];
    for (int k = 0; k < 2 * DDIM; k++) {
        const float x = inb[nl][k];
        float4 w = ((const float4*)(u1 + k * DDIM))[l];
        z.x += x * w.x; z.y += x * w.y; z.z += x * w.z; z.w += x * w.w;
    }
    z.x = fmaxf(z.x, 0.f); z.y = fmaxf(z.y, 0.f);
    z.z = fmaxf(z.z, 0.f); z.w = fmaxf(z.w, 0.f);

    // ---- output layer: partial (o0,o1), reduce across the 16 lanes ----
    const int j0 = 4 * l;
    float o0 = z.x * u2[2 * (j0 + 0)] + z.y * u2[2 * (j0 + 1)]
             + z.z * u2[2 * (j0 + 2)] + z.w * u2[2 * (j0 + 3)];
    float o1 = z.x * u2[2 * (j0 + 0) + 1] + z.y * u2[2 * (j0 + 1) + 1]
             + z.z * u2[2 * (j0 + 2) + 1] + z.w * u2[2 * (j0 + 3) + 1];
#pragma unroll
    for (int m = 1; m < 16; m <<= 1) {
        o0 += __shfl_xor(o0, m, 64);
        o1 += __shfl_xor(o1, m, 64);
    }
    if (valid && l == 0)
        ((float2*)out)[node] = make_float2(o0 + cc2v[0], o1 + cc2v[1]);
}

// ---------------------------------------------------------------------------
extern "C" void kernel_launch(void* const* d_in, const int* in_sizes, int n_in,
                              void* d_out, int out_size, void* d_ws, size_t ws_size,
                              hipStream_t stream) {
    const float* h    = (const float*)d_in[0];
    const int*   eidx = (const int*)d_in[1];
    const float* W1   = (const float*)d_in[2];
    const float* b1   = (const float*)d_in[3];
    const float* W2   = (const float*)d_in[4];
    const float* b2   = (const float*)d_in[5];
    const float* U1   = (const float*)d_in[6];
    const float* c1   = (const float*)d_in[7];
    const float* U2   = (const float*)d_in[8];
    const float* c2   = (const float*)d_in[9];

    const int n_nodes = in_sizes[0] / DDIM;     // 100000
    const int n_edges = in_sizes[1] / 2;        // 1600000

    // workspace layout
    float* M        = (float*)d_ws;                       // N*64 f32 (25.6 MB)
    u32*   deg      = (u32*)(M + (size_t)n_nodes * DDIM); // N
    u32*   cursor   = deg + n_nodes;                      // N
    u32*   offsets  = cursor + n_nodes;                   // N+1
    u32*   bsums    = offsets + (n_nodes + 1);            // <=1024
    u32*   csr_col  = bsums + 1024;                       // E (6.4 MB)

    float* out = (float*)d_out;

    // zero deg + cursor (contiguous)
    hipMemsetAsync(deg, 0, 2 * (size_t)n_nodes * sizeof(u32), stream);

    const int nblk_nodes = (n_nodes + 255) / 256;   // 391
    const int nblk_edges = (n_edges + 255) / 256;   // 6250

    node_mlp<<<nblk_nodes, 256, 0, stream>>>(h, W1, b1, W2, b2, M, n_nodes);
    hist_rows<<<nblk_edges, 256, 0, stream>>>(eidx, deg, n_edges);
    scan_blocks<<<nblk_nodes, 256, 0, stream>>>(deg, offsets, bsums, n_nodes);
    scan_top<<<1, 512, 0, stream>>>(bsums, nblk_nodes);
    add_base<<<nblk_nodes, 256, 0, stream>>>(offsets, bsums, n_nodes, n_edges);
    fill_csr<<<nblk_edges, 256, 0, stream>>>(eidx, offsets, cursor, csr_col, n_edges);

    const int nblk_gu = (n_nodes + 15) / 16;        // 6250
    gather_update<<<nblk_gu, 256, 0, stream>>>(h, M, offsets, csr_col,
                                               U1, c1, U2, c2, out, n_nodes);
}

// Round 3
// 394.428 us; speedup vs baseline: 4.1045x; 1.1509x over previous
//
#include <hip/hip_runtime.h>
#include <hip/hip_bf16.h>

#define DDIM 64
typedef unsigned int u32;
typedef unsigned short u16;

typedef __attribute__((ext_vector_type(8))) short short8;
typedef __attribute__((ext_vector_type(4))) float f32x4;

__device__ __forceinline__ float bf2f(u16 x) {
    union { u32 u; float f; } c; c.u = ((u32)x) << 16; return c.f;
}
__device__ __forceinline__ u16 f2bf(float f) {
    union { float f; u32 u; } c; c.f = f;
    const u32 u = c.u;
    return (u16)((u + 0x7fffu + ((u >> 16) & 1u)) >> 16);   // round-nearest-even
}

// ---------------------------------------------------------------------------
// Kernel A: per-node message MLP via MFMA bf16.
//   M = relu(relu(h@W1+b1)@W2+b2), stored bf16 (halves the gather bytes).
// Block = 256 thr = 4 waves = 64 nodes; wave w owns nodes [w*16, w*16+16).
// Layouts (gfx950 16x16x32 bf16, HW-verified):
//   A[m][k]: m=lane&15, k=(lane>>4)*8+j   -> ds_read_b128 from row-major rows
//   C/D:     col=lane&15, row=(lane>>4)*4+reg
// Layer1->layer2 relayout through wave-private LDS rows (no barrier needed).
// ---------------------------------------------------------------------------
#define NSTRIDE 72   // shorts per LDS row (144 B: 16B-aligned, bank-staggered)

__global__ __launch_bounds__(256) void node_mlp_mfma(
    const float* __restrict__ h,
    const float* __restrict__ W1, const float* __restrict__ b1,
    const float* __restrict__ W2, const float* __restrict__ b2,
    u16* __restrict__ M, int n_nodes)
{
    __shared__ u16 hs[DDIM * NSTRIDE];     // h tile (bf16); reused for output
    __shared__ u16 zs[DDIM * NSTRIDE];     // layer-1 activations
    __shared__ u16 wt1[DDIM * NSTRIDE];    // W1^T [n][k]
    __shared__ u16 wt2[DDIM * NSTRIDE];    // W2^T [n][k]
    __shared__ float bb1[DDIM], bb2[DDIM];

    const int t = threadIdx.x;
    const int node0 = blockIdx.x * DDIM;
    const int nvalid = min(DDIM, n_nodes - node0);

    // stage h -> bf16 (coalesced float4 reads)
    for (int idx = t; idx < DDIM * (DDIM / 4); idx += 256) {
        const int r = idx >> 4, c4 = idx & 15;
        if (r < nvalid) {
            float4 v = ((const float4*)h)[(size_t)(node0 + r) * (DDIM / 4) + c4];
            u16* dst = &hs[r * NSTRIDE + c4 * 4];
            dst[0] = f2bf(v.x); dst[1] = f2bf(v.y);
            dst[2] = f2bf(v.z); dst[3] = f2bf(v.w);
        }
    }
    // stage W^T (coalesced global reads, scattered LDS writes — tiny)
    for (int idx = t; idx < DDIM * DDIM; idx += 256) {
        const int k = idx >> 6, n = idx & 63;
        wt1[n * NSTRIDE + k] = f2bf(W1[k * DDIM + n]);
        wt2[n * NSTRIDE + k] = f2bf(W2[k * DDIM + n]);
    }
    if (t < DDIM) { bb1[t] = b1[t]; bb2[t] = b2[t]; }
    __syncthreads();

    const int wave = t >> 6;
    const int lane = t & 63;
    const int mc   = lane & 15;      // A row / B col / C col within tile
    const int quad = lane >> 4;

    // ---- layer 1 ----
    const int arow = (wave * 16 + mc) * NSTRIDE + quad * 8;
    short8 a0 = *(const short8*)&hs[arow];
    short8 a1 = *(const short8*)&hs[arow + 32];
#pragma unroll
    for (int nt = 0; nt < 4; nt++) {
        const int brow = (nt * 16 + mc) * NSTRIDE + quad * 8;
        short8 w0 = *(const short8*)&wt1[brow];
        short8 w1v = *(const short8*)&wt1[brow + 32];
        f32x4 c = {0.f, 0.f, 0.f, 0.f};
        c = __builtin_amdgcn_mfma_f32_16x16x32_bf16(a0, w0, c, 0, 0, 0);
        c = __builtin_amdgcn_mfma_f32_16x16x32_bf16(a1, w1v, c, 0, 0, 0);
        const float bias = bb1[nt * 16 + mc];
#pragma unroll
        for (int r = 0; r < 4; r++) {
            const int row = wave * 16 + quad * 4 + r;            // wave-private
            zs[row * NSTRIDE + nt * 16 + mc] = f2bf(fmaxf(c[r] + bias, 0.f));
        }
    }

    // ---- layer 2 (A from zs, same wave-private rows) ----
    short8 a2 = *(const short8*)&zs[arow];
    short8 a3 = *(const short8*)&zs[arow + 32];
#pragma unroll
    for (int nt = 0; nt < 4; nt++) {
        const int brow = (nt * 16 + mc) * NSTRIDE + quad * 8;
        short8 w0 = *(const short8*)&wt2[brow];
        short8 w1v = *(const short8*)&wt2[brow + 32];
        f32x4 c = {0.f, 0.f, 0.f, 0.f};
        c = __builtin_amdgcn_mfma_f32_16x16x32_bf16(a2, w0, c, 0, 0, 0);
        c = __builtin_amdgcn_mfma_f32_16x16x32_bf16(a3, w1v, c, 0, 0, 0);
        const float bias = bb2[nt * 16 + mc];
#pragma unroll
        for (int r = 0; r < 4; r++) {
            const int row = wave * 16 + quad * 4 + r;
            hs[row * NSTRIDE + nt * 16 + mc] = f2bf(fmaxf(c[r] + bias, 0.f));
        }
    }
    __syncthreads();

    // coalesced bf16 write-out (ushort4 = 8B per thread-chunk)
    for (int idx = t; idx < DDIM * (DDIM / 4); idx += 256) {
        const int r = idx >> 4, c4 = idx & 15;
        if (r < nvalid) {
            *(ushort4*)&M[(size_t)(node0 + r) * DDIM + c4 * 4] =
                *(const ushort4*)&hs[r * NSTRIDE + c4 * 4];
        }
    }
}

// ---------------------------------------------------------------------------
// CSR construction: histogram -> exclusive scan -> counting-sort fill
// ---------------------------------------------------------------------------
__global__ __launch_bounds__(256) void hist_rows(
    const int* __restrict__ eidx, u32* __restrict__ deg, int n_edges)
{
    const int e = blockIdx.x * 256 + threadIdx.x;
    if (e < n_edges) atomicAdd(&deg[eidx[e]], 1u);
}

__global__ __launch_bounds__(256) void scan_blocks(
    const u32* __restrict__ deg, u32* __restrict__ offsets,
    u32* __restrict__ bsums, int n)
{
    __shared__ u32 s[256];
    const int t = threadIdx.x;
    const int gid = blockIdx.x * 256 + t;
    u32 v = (gid < n) ? deg[gid] : 0u;
    s[t] = v;
    __syncthreads();
    for (int off = 1; off < 256; off <<= 1) {
        u32 x = (t >= off) ? s[t - off] : 0u;
        __syncthreads();
        s[t] += x;
        __syncthreads();
    }
    if (gid < n) offsets[gid] = s[t] - v;
    if (t == 255) bsums[blockIdx.x] = s[255];
}

__global__ __launch_bounds__(512) void scan_top(u32* __restrict__ bsums, int nb)
{
    __shared__ u32 s[512];
    const int t = threadIdx.x;
    u32 v = (t < nb) ? bsums[t] : 0u;
    s[t] = v;
    __syncthreads();
    for (int off = 1; off < 512; off <<= 1) {
        u32 x = (t >= off) ? s[t - off] : 0u;
        __syncthreads();
        s[t] += x;
        __syncthreads();
    }
    if (t < nb) bsums[t] = s[t] - v;
}

__global__ __launch_bounds__(256) void add_base(
    u32* __restrict__ offsets, const u32* __restrict__ bsums,
    u32* __restrict__ cursor, int n, int n_edges)
{
    const int gid = blockIdx.x * 256 + threadIdx.x;
    if (gid < n) {
        const u32 o = offsets[gid] + bsums[blockIdx.x];
        offsets[gid] = o;
        cursor[gid]  = o;            // cursor starts at row base (absolute slots)
    }
    if (gid == 0) offsets[n] = (u32)n_edges;
}

__global__ __launch_bounds__(256) void fill_csr(
    const int* __restrict__ eidx, u32* __restrict__ cursor,
    u32* __restrict__ csr_col, int n_edges)
{
    const int e = blockIdx.x * 256 + threadIdx.x;
    if (e >= n_edges) return;
    const int row = eidx[e];
    const int col = eidx[n_edges + e];
    const u32 slot = atomicAdd(&cursor[row], 1u);
    csr_col[slot] = (u32)col;
}

// ---------------------------------------------------------------------------
// Fused gather + update MLP.  512 thr = 32 nodes/block, 16 lanes/node.
//   agg = mean_{col in CSR[node]} M_bf16[col]   (gather unrolled x2 for ILP)
//   z = relu([h, agg] @ U1 + c1);  out = z @ U2 + c2
// ---------------------------------------------------------------------------
#define INPAD 132   // 128 + 4: the 4 node-groups of a wave hit distinct banks
#define NODES_PER_BLK 32

__global__ __launch_bounds__(512) void gather_update(
    const float* __restrict__ h, const u16* __restrict__ M,
    const u32* __restrict__ offsets, const u32* __restrict__ csr_col,
    const float* __restrict__ U1, const float* __restrict__ c1,
    const float* __restrict__ U2, const float* __restrict__ c2,
    float* __restrict__ out, int n_nodes)
{
    __shared__ __align__(16) float u1[2 * DDIM * DDIM];      // 32 KB
    __shared__ __align__(16) float inb[NODES_PER_BLK][INPAD]; // 16.5 KB
    __shared__ float cc1[DDIM];
    __shared__ float u2[DDIM * 2];
    __shared__ float cc2v[2];

    const int t = threadIdx.x;
    {
        const float4* src = (const float4*)U1;
        float4* dst = (float4*)u1;
        for (int i = t; i < 2 * DDIM * DDIM / 4; i += 512) dst[i] = src[i];
    }
    if (t < DDIM) cc1[t] = c1[t];
    if (t < DDIM * 2) u2[t] = U2[t];
    if (t < 2) cc2v[t] = c2[t];

    const int nl = t >> 4;          // node-local 0..31
    const int l  = t & 15;          // lane within node (owns cols 4l..4l+3)
    const int node = blockIdx.x * NODES_PER_BLK + nl;
    const bool valid = node < n_nodes;

    float ax = 0.f, ay = 0.f, az = 0.f, aw = 0.f;
    u32 beg = 0, end = 0;
    if (valid) { beg = offsets[node]; end = offsets[node + 1]; }

    u32 i = beg;
    for (; i + 1 < end; i += 2) {       // 2 gathers in flight
        const u32 c0 = csr_col[i];
        const u32 c1i = csr_col[i + 1];
        ushort4 v0 = ((const ushort4*)M)[(size_t)c0 * 16 + l];
        ushort4 v1 = ((const ushort4*)M)[(size_t)c1i * 16 + l];
        ax += bf2f(v0.x) + bf2f(v1.x);
        ay += bf2f(v0.y) + bf2f(v1.y);
        az += bf2f(v0.z) + bf2f(v1.z);
        aw += bf2f(v0.w) + bf2f(v1.w);
    }
    if (i < end) {
        const u32 c0 = csr_col[i];
        ushort4 v0 = ((const ushort4*)M)[(size_t)c0 * 16 + l];
        ax += bf2f(v0.x); ay += bf2f(v0.y);
        az += bf2f(v0.z); aw += bf2f(v0.w);
    }
    const float dn = 1.0f / fmaxf((float)(end - beg), 1.0f);

    if (valid) {
        float4 hv = ((const float4*)h)[(size_t)node * (DDIM / 4) + l];
        ((float4*)&inb[nl][0])[l] = hv;
        ((float4*)&inb[nl][DDIM])[l] = make_float4(ax * dn, ay * dn, az * dn, aw * dn);
    }
    __syncthreads();

    // layer 1: lane computes z[4l..4l+3]
    float4 z = ((const float4*)cc1)[l];
    for (int k = 0; k < 2 * DDIM; k++) {
        const float x = inb[nl][k];
        float4 w = ((const float4*)(u1 + k * DDIM))[l];
        z.x += x * w.x; z.y += x * w.y; z.z += x * w.z; z.w += x * w.w;
    }
    z.x = fmaxf(z.x, 0.f); z.y = fmaxf(z.y, 0.f);
    z.z = fmaxf(z.z, 0.f); z.w = fmaxf(z.w, 0.f);

    // output layer: partial (o0,o1), butterfly-reduce across the 16 lanes
    const int j0 = 4 * l;
    float o0 = z.x * u2[2 * (j0 + 0)] + z.y * u2[2 * (j0 + 1)]
             + z.z * u2[2 * (j0 + 2)] + z.w * u2[2 * (j0 + 3)];
    float o1 = z.x * u2[2 * (j0 + 0) + 1] + z.y * u2[2 * (j0 + 1) + 1]
             + z.z * u2[2 * (j0 + 2) + 1] + z.w * u2[2 * (j0 + 3) + 1];
#pragma unroll
    for (int m = 1; m < 16; m <<= 1) {
        o0 += __shfl_xor(o0, m, 64);
        o1 += __shfl_xor(o1, m, 64);
    }
    if (valid && l == 0)
        ((float2*)out)[node] = make_float2(o0 + cc2v[0], o1 + cc2v[1]);
}

// ---------------------------------------------------------------------------
extern "C" void kernel_launch(void* const* d_in, const int* in_sizes, int n_in,
                              void* d_out, int out_size, void* d_ws, size_t ws_size,
                              hipStream_t stream) {
    const float* h    = (const float*)d_in[0];
    const int*   eidx = (const int*)d_in[1];
    const float* W1   = (const float*)d_in[2];
    const float* b1   = (const float*)d_in[3];
    const float* W2   = (const float*)d_in[4];
    const float* b2   = (const float*)d_in[5];
    const float* U1   = (const float*)d_in[6];
    const float* c1   = (const float*)d_in[7];
    const float* U2   = (const float*)d_in[8];
    const float* c2   = (const float*)d_in[9];

    const int n_nodes = in_sizes[0] / DDIM;     // 100000
    const int n_edges = in_sizes[1] / 2;        // 1600000

    // workspace layout
    u16*   M       = (u16*)d_ws;                              // N*64 bf16 (12.8 MB)
    u32*   deg     = (u32*)(M + (size_t)n_nodes * DDIM);      // N
    u32*   cursor  = deg + n_nodes;                           // N
    u32*   offsets = cursor + n_nodes;                        // N+1
    u32*   bsums   = offsets + (n_nodes + 1);                 // <=1024
    u32*   csr_col = bsums + 1024;                            // E (6.4 MB)

    float* out = (float*)d_out;

    hipMemsetAsync(deg, 0, (size_t)n_nodes * sizeof(u32), stream);

    const int nblk_scan  = (n_nodes + 255) / 256;             // 391
    const int nblk_edges = (n_edges + 255) / 256;             // 6250
    const int nblk_mlp   = (n_nodes + DDIM - 1) / DDIM;       // 1563

    node_mlp_mfma<<<nblk_mlp, 256, 0, stream>>>(h, W1, b1, W2, b2, M, n_nodes);
    hist_rows<<<nblk_edges, 256, 0, stream>>>(eidx, deg, n_edges);
    scan_blocks<<<nblk_scan, 256, 0, stream>>>(deg, offsets, bsums, n_nodes);
    scan_top<<<1, 512, 0, stream>>>(bsums, nblk_scan);
    add_base<<<nblk_scan, 256, 0, stream>>>(offsets, bsums, cursor, n_nodes, n_edges);
    fill_csr<<<nblk_edges, 256, 0, stream>>>(eidx, cursor, csr_col, n_edges);

    const int nblk_gu = (n_nodes + NODES_PER_BLK - 1) / NODES_PER_BLK;  // 3125
    gather_update<<<nblk_gu, 512, 0, stream>>>(h, M, offsets, csr_col,
                                               U1, c1, U2, c2, out, n_nodes);
}